// Round 17
// baseline (80.002 us; speedup 1.0000x reference)
//
#include <hip/hip_runtime.h>
#include <math.h>

// LogicConv2d, SINGLE-LAUNCH: block 0 builds the weight table in d_ws,
// all other blocks spin (overlapped with their staging DMA) on a
// device-scope flag. Removes the prep kernel node + graph node transition
// (R13/R16 lesson: per-replay serial overhead is the only lever left —
// all pipes idle, working set L3-resident, nt stores fixed write pollution).
//
// tab[81][24] floats: q0=sa[0:4] q1=sa[4:8] q2={sa8,sb0,sb1,sb2}
// q3=sb[3:7] q4={sb7,sb8,Cab,Ca} q5={Cb,C0,-,-}; flag at float idx 1944.
// Mix collapsed: out = Cab*ab + Ca*a + Cb*b + C0.
//
// 1792 blocks (7/CU = exact residency -> co-residency guaranteed -> spin is
// deadlock-free) x 256 threads. Tile t0 = bid for all; blocks 1536..1791
// additionally do tile bid+256 (keeps prep-burdened block 0 single-loaded).
// Per tile: global_load_lds DMA stage -> barrier -> [first tile: flag spin]
// -> compute (wave w<3 owns units 27w..27w+26 == patch-row w; 27 inputs in
// regs; weights via wave-uniform float4 loads, L2-hot; fully unrolled;
// in-place tile) -> barrier -> non-temporal coalesced writeback.

#define NB      131072
#define NUNITS  81
#define BPB     64             // batches per tile
#define THREADS 256
#define NTILES  (NB / BPB)     // 2048
#define PBLK    1792           // 7 per CU x 256 CUs = exact residency
#define REC     24             // floats per unit record (96 B)
#define CHUNKS  (BPB * 81 / 4) // 1296 float4 per tile
#define TABF    (NUNITS * REC) // 1944 floats

typedef __attribute__((address_space(1))) const void GAS;
typedef __attribute__((address_space(3))) void LAS;
typedef float vfloat4 __attribute__((ext_vector_type(4)));

__device__ __forceinline__
void stage_tile(const float* __restrict__ x, float* __restrict__ s_tile,
                int tid, int wavei, size_t b0)
{
    const float4* gsrc = (const float4*)(x + b0 * 81);
    #pragma unroll
    for (int k = 0; k < 6; ++k) {
        const int j = tid + k * THREADS;
        if (j < CHUNKS) {
            // wave-uniform LDS base; hardware adds lane*16
            float* lbase = s_tile + (size_t)(k * THREADS + wavei * 64) * 4;
            __builtin_amdgcn_global_load_lds((GAS*)(gsrc + j), (LAS*)lbase,
                                             16, 0, 0);
        }
    }
}

__device__ __forceinline__
void compute_tile(float* __restrict__ s_tile, const float* __restrict__ tab,
                  int lane, int wavei)
{
    if (wavei < 3) {
        float* my = s_tile + lane * 81 + wavei * 27;    // read == write slice

        float in[27];                                    // img rows 3w..3w+2
        #pragma unroll
        for (int j = 0; j < 27; ++j) in[j] = my[j];

        const float4* __restrict__ wt4 =
            (const float4*)(tab + (size_t)wavei * 27 * REC);  // uniform base

        #pragma unroll
        for (int j = 0; j < 27; ++j) {                   // unit u = 27*wavei+j
            const int q = j / 9;                         // patch col within row
            const float4 q0 = wt4[j * 6 + 0];
            const float4 q1 = wt4[j * 6 + 1];
            const float4 q2 = wt4[j * 6 + 2];
            const float4 q3 = wt4[j * 6 + 3];
            const float4 q4 = wt4[j * 6 + 4];
            const float4 q5 = wt4[j * 6 + 5];
            const float wa[9] = { q0.x, q0.y, q0.z, q0.w, q1.x, q1.y, q1.z, q1.w, q2.x };
            const float wb[9] = { q2.y, q2.z, q2.w, q3.x, q3.y, q3.z, q3.w, q4.x, q4.y };
            float a = 0.f, b = 0.f;
            #pragma unroll
            for (int i = 0; i < 9; ++i) {
                const float xi = in[q * 3 + (i / 3) * 9 + (i % 3)];
                a = fmaf(xi, wa[i], a);
                b = fmaf(xi, wb[i], b);
            }
            // q4.z=Cab q4.w=Ca q5.x=Cb q5.y=C0
            my[j] = fmaf(q4.z, a * b, fmaf(q4.w, a, fmaf(q5.x, b, q5.y)));
        }
    }
}

__device__ __forceinline__
void writeback_tile(const float* __restrict__ s_tile, float* __restrict__ out,
                    int tid, size_t b0)
{
    const vfloat4* s4 = (const vfloat4*)s_tile;
    vfloat4* gdst = (vfloat4*)(out + b0 * 81);
    #pragma unroll
    for (int k = 0; k < 6; ++k) {
        const int j = tid + k * THREADS;
        if (j < CHUNKS) __builtin_nontemporal_store(s4[j], gdst + j);
    }
}

__global__ __launch_bounds__(THREADS, 7)
void logic_all_kernel(const float* __restrict__ x,
                      const float* __restrict__ sa_logits,
                      const float* __restrict__ sb_logits,
                      const float* __restrict__ op_logits,
                      float* __restrict__ tab,
                      int* __restrict__ flag,
                      float* __restrict__ out)
{
    __shared__ float s_tile[BPB * 81];     // 20736 B — the only LDS

    const int tid   = threadIdx.x;
    const int lane  = tid & 63;
    const int wavei = __builtin_amdgcn_readfirstlane(tid >> 6);
    const int bid   = blockIdx.x;

    // ---- block 0: build the weight table, publish via device-scope flag ----
    if (bid == 0) {
        if (tid < 81) {
            const int u = tid;
            float v[9], m = -1e30f;
            #pragma unroll
            for (int i = 0; i < 9; ++i) { v[i] = sa_logits[u * 9 + i]; m = fmaxf(m, v[i]); }
            float s = 0.f;
            #pragma unroll
            for (int i = 0; i < 9; ++i) { v[i] = expf(v[i] - m); s += v[i]; }
            const float r = 1.f / s;
            #pragma unroll
            for (int i = 0; i < 9; ++i) tab[u * REC + i] = v[i] * r;
        } else if (tid < 162) {
            const int u = tid - 81;
            float v[9], m = -1e30f;
            #pragma unroll
            for (int i = 0; i < 9; ++i) { v[i] = sb_logits[u * 9 + i]; m = fmaxf(m, v[i]); }
            float s = 0.f;
            #pragma unroll
            for (int i = 0; i < 9; ++i) { v[i] = expf(v[i] - m); s += v[i]; }
            const float r = 1.f / s;
            #pragma unroll
            for (int i = 0; i < 9; ++i) tab[u * REC + 9 + i] = v[i] * r;
        } else if (tid < 243) {
            const int u = tid - 162;
            float v[16], m = -1e30f;
            #pragma unroll
            for (int i = 0; i < 16; ++i) { v[i] = op_logits[u * 16 + i]; m = fmaxf(m, v[i]); }
            float s = 0.f;
            #pragma unroll
            for (int i = 0; i < 16; ++i) { v[i] = expf(v[i] - m); s += v[i]; }
            const float r = 1.f / s;
            #pragma unroll
            for (int i = 0; i < 16; ++i) v[i] *= r;
            const float cab = v[1] - v[2] - v[4] - 2.f*v[6] - v[7] + v[8] + 2.f*v[9]
                            + v[11] + v[13] - v[14];
            const float ca  = v[2] + v[3] + v[6] + v[7] - v[8] - v[9] - v[12] - v[13];
            const float cb  = v[4] + v[5] + v[6] + v[7] - v[8] - v[9] - v[10] - v[11];
            const float c0  = v[8] + v[9] + v[10] + v[11] + v[12] + v[13] + v[14] + v[15];
            tab[u * REC + 18] = cab;
            tab[u * REC + 19] = ca;
            tab[u * REC + 20] = cb;
            tab[u * REC + 21] = c0;
        }
        __syncthreads();
        if (tid == 0)
            __hip_atomic_store(flag, 1, __ATOMIC_RELEASE, __HIP_MEMORY_SCOPE_AGENT);
    }

    // ================= tile 0: t = bid =================
    stage_tile(x, s_tile, tid, wavei, (size_t)bid * BPB);
    __syncthreads();

    // wait for the table (overlapped with the DMA above; block 0 passes through)
    if (tid == 0) {
        while (__hip_atomic_load(flag, __ATOMIC_ACQUIRE,
                                 __HIP_MEMORY_SCOPE_AGENT) == 0)
            __builtin_amdgcn_s_sleep(8);
    }
    __syncthreads();

    compute_tile(s_tile, tab, lane, wavei);
    __syncthreads();
    writeback_tile(s_tile, out, tid, (size_t)bid * BPB);

    // ================= tile 1: blocks 1536..1791 take tiles 1792..2047 ====
    if (bid >= PBLK - 256) {
        __syncthreads();   // writeback ds_reads done before re-staging
        const size_t b1 = (size_t)(bid + 256) * BPB;
        stage_tile(x, s_tile, tid, wavei, b1);
        __syncthreads();
        compute_tile(s_tile, tab, lane, wavei);
        __syncthreads();
        writeback_tile(s_tile, out, tid, b1);
    }
}

extern "C" void kernel_launch(void* const* d_in, const int* in_sizes, int n_in,
                              void* d_out, int out_size, void* d_ws, size_t ws_size,
                              hipStream_t stream)
{
    const float* x  = (const float*)d_in[0];
    const float* sa = (const float*)d_in[1];
    const float* sb = (const float*)d_in[2];
    const float* op = (const float*)d_in[3];
    float* tab  = (float*)d_ws;                 // 1944 floats
    int*   flag = (int*)((float*)d_ws + TABF);  // 4 B after tab
    float* outp = (float*)d_out;

    hipMemsetAsync(flag, 0, sizeof(int), stream);   // reset publish flag
    logic_all_kernel<<<PBLK, THREADS, 0, stream>>>(x, sa, sb, op, tab, flag, outp);
}

// Round 18
// 43.050 us; speedup vs baseline: 1.8584x; 1.8584x over previous
//
#include <hip/hip_runtime.h>
#include <math.h>

// LogicConv2d, single fused persistent kernel, 7 blocks/CU.
//
// Every block builds the collapsed weight table in its own LDS (all 256
// threads, ~11 expf each), issued AFTER the first tile's global_load_lds
// DMA so the build hides under DMA latency (R14's build-hiding was sound;
// its loss was occupancy 7->5). 7/CU is preserved by shrinking LDS to
// 22680 B: tile 48x81 floats (15552 B) + table 81x22 floats (7128 B, no
// padding; weight-read path is cost-insensitive per R4-R8).
//   table record u: [0..9)=softmax(sel_a), [9..18)=softmax(sel_b),
//   18=Cab 19=Ca 20=Cb 21=C0  (mix collapsed: out = Cab*ab+Ca*a+Cb*b+C0).
//
// Persistent grid 1792 (7/CU x 256 CU); tiles t = bid, bid+1792 over 2731
// tiles of 48 batches (last tile 32). Per tile: DMA stage -> barrier ->
// compute (wave w<3, lanes<nb: unit slice 27w..27w+26 == patch-row w; 27
// inputs hoisted to regs; weights via wave-uniform ds_read broadcast,
// fully unrolled; in-place tile) -> barrier -> non-temporal float4
// writeback -> barrier (LDS protect).

#define NB      131072
#define NUNITS  81
#define BPB     48             // batches per tile
#define THREADS 256
#define NTILES  2731           // 2730 full + 1 partial (32 batches)
#define PBLK    1792           // 7 per CU x 256 CUs
#define WREC    22             // floats per unit record (88 B)
#define LASTB   (NB - (NTILES - 1) * BPB)   // 32

typedef __attribute__((address_space(1))) const void GAS;
typedef __attribute__((address_space(3))) void LAS;
typedef float vfloat4 __attribute__((ext_vector_type(4)));

__global__ __launch_bounds__(THREADS, 7)
void logic_fused_kernel(const float* __restrict__ x,
                        const float* __restrict__ sa_logits,
                        const float* __restrict__ sb_logits,
                        const float* __restrict__ op_logits,
                        float* __restrict__ out)
{
    __shared__ float s_tile[BPB * 81];      // 15552 B
    __shared__ float s_w[NUNITS * WREC];    //  7128 B   (total 22680 B -> 7/CU)

    const int tid   = threadIdx.x;
    const int lane  = tid & 63;
    const int wavei = __builtin_amdgcn_readfirstlane(tid >> 6);
    const int bid   = blockIdx.x;

    bool first = true;
    for (int t = bid; t < NTILES; t += PBLK) {
        const int nb      = (t == NTILES - 1) ? LASTB : BPB;
        const int nchunks = nb * 81 / 4;            // 972 or 648
        const size_t b0   = (size_t)t * BPB;

        if (!first) __syncthreads();                // LDS protect vs prev writeback

        // ---- stage tile via global->LDS DMA ----
        {
            const float4* gsrc = (const float4*)(x + b0 * 81);
            #pragma unroll
            for (int k = 0; k < 4; ++k) {
                const int j = tid + k * THREADS;
                if (j < nchunks) {
                    // wave-uniform LDS base; hardware adds lane*16
                    float* lbase = s_tile + (size_t)(k * THREADS + wavei * 64) * 4;
                    __builtin_amdgcn_global_load_lds((GAS*)(gsrc + j), (LAS*)lbase,
                                                     16, 0, 0);
                }
            }
        }

        // ---- first iteration only: build weight table (hides under DMA) ----
        if (first) {
            first = false;
            if (tid < 81) {
                const int u = tid;
                float v[9], m = -1e30f;
                #pragma unroll
                for (int i = 0; i < 9; ++i) { v[i] = sa_logits[u * 9 + i]; m = fmaxf(m, v[i]); }
                float s = 0.f;
                #pragma unroll
                for (int i = 0; i < 9; ++i) { v[i] = expf(v[i] - m); s += v[i]; }
                const float r = 1.f / s;
                #pragma unroll
                for (int i = 0; i < 9; ++i) s_w[u * WREC + i] = v[i] * r;
            } else if (tid < 162) {
                const int u = tid - 81;
                float v[9], m = -1e30f;
                #pragma unroll
                for (int i = 0; i < 9; ++i) { v[i] = sb_logits[u * 9 + i]; m = fmaxf(m, v[i]); }
                float s = 0.f;
                #pragma unroll
                for (int i = 0; i < 9; ++i) { v[i] = expf(v[i] - m); s += v[i]; }
                const float r = 1.f / s;
                #pragma unroll
                for (int i = 0; i < 9; ++i) s_w[u * WREC + 9 + i] = v[i] * r;
            } else if (tid < 243) {
                const int u = tid - 162;
                float v[16], m = -1e30f;
                #pragma unroll
                for (int i = 0; i < 16; ++i) { v[i] = op_logits[u * 16 + i]; m = fmaxf(m, v[i]); }
                float s = 0.f;
                #pragma unroll
                for (int i = 0; i < 16; ++i) { v[i] = expf(v[i] - m); s += v[i]; }
                const float r = 1.f / s;
                #pragma unroll
                for (int i = 0; i < 16; ++i) v[i] *= r;
                const float cab = v[1] - v[2] - v[4] - 2.f*v[6] - v[7] + v[8] + 2.f*v[9]
                                + v[11] + v[13] - v[14];
                const float ca  = v[2] + v[3] + v[6] + v[7] - v[8] - v[9] - v[12] - v[13];
                const float cb  = v[4] + v[5] + v[6] + v[7] - v[8] - v[9] - v[10] - v[11];
                const float c0  = v[8] + v[9] + v[10] + v[11] + v[12] + v[13] + v[14] + v[15];
                s_w[u * WREC + 18] = cab;
                s_w[u * WREC + 19] = ca;
                s_w[u * WREC + 20] = cb;
                s_w[u * WREC + 21] = c0;
            }
        }

        __syncthreads();   // DMA complete + table built

        // ---- compute: wave w<3, lanes<nb; units 27w..27w+26 == patch-row w ----
        if (wavei < 3 && lane < nb) {
            float* my = s_tile + lane * 81 + wavei * 27;   // read == write slice

            float in[27];                                   // img rows 3w..3w+2
            #pragma unroll
            for (int j = 0; j < 27; ++j) in[j] = my[j];

            const float* __restrict__ wt = s_w + wavei * 27 * WREC;  // uniform base

            #pragma unroll
            for (int j = 0; j < 27; ++j) {                  // unit u = 27*wavei+j
                const int q = j / 9;                        // patch col within row
                const float* __restrict__ wr = wt + j * WREC;  // broadcast ds_read
                float a = 0.f, b = 0.f;
                #pragma unroll
                for (int i = 0; i < 9; ++i) {
                    const float xi = in[q * 3 + (i / 3) * 9 + (i % 3)];
                    a = fmaf(xi, wr[i],     a);
                    b = fmaf(xi, wr[9 + i], b);
                }
                my[j] = fmaf(wr[18], a * b, fmaf(wr[19], a, fmaf(wr[20], b, wr[21])));
            }
        }

        __syncthreads();

        // ---- coalesced non-temporal writeback ----
        {
            const vfloat4* s4 = (const vfloat4*)s_tile;
            vfloat4* gdst = (vfloat4*)(out + b0 * 81);
            #pragma unroll
            for (int k = 0; k < 4; ++k) {
                const int j = tid + k * THREADS;
                if (j < nchunks) __builtin_nontemporal_store(s4[j], gdst + j);
            }
        }
    }
}

extern "C" void kernel_launch(void* const* d_in, const int* in_sizes, int n_in,
                              void* d_out, int out_size, void* d_ws, size_t ws_size,
                              hipStream_t stream)
{
    const float* x  = (const float*)d_in[0];
    const float* sa = (const float*)d_in[1];
    const float* sb = (const float*)d_in[2];
    const float* op = (const float*)d_in[3];
    float* outp = (float*)d_out;

    logic_fused_kernel<<<PBLK, THREADS, 0, stream>>>(x, sa, sb, op, outp);
}

// Round 19
// 28.758 us; speedup vs baseline: 2.7819x; 1.4970x over previous
//
#include <hip/hip_runtime.h>
#include <math.h>

// LogicConv2d, prep + BALANCED persistent main (2 tiles/block exactly).
//
// prep (1 block): softmax(sel_a), softmax(sel_b), collapse 16-way mix to
//   out = Cab*ab + Ca*a + Cb*b + C0. tab[81][24] floats in d_ws, readable
//   as 6 aligned float4 per unit: q0=sa[0:4] q1=sa[4:8] q2={sa8,sb0,sb1,sb2}
//   q3=sb[3:7] q4={sb7,sb8,Cab,Ca} q5={Cb,C0,-,-}.
//
// main: 2048 blocks = EXACTLY 8/CU (LDS 10.4 KB, 32-wave cap) x 256 thr;
//   each block does exactly 2 contiguous tiles of 32 batches (t = 2*bid,
//   2*bid+1) — R16's 2048-on-1792 imbalance ran round 2 at 1/7 occupancy;
//   this is fully balanced, both rounds whole-chip. Per tile:
//   global_load_lds DMA stage -> barrier -> compute (wave w<3, lanes<32:
//   units 27w..27w+26 == patch-row w; 27 inputs in regs; weights via
//   wave-uniform float4 loads from d_ws, L2-hot; fully unrolled; in-place
//   tile) -> barrier -> NON-TEMPORAL coalesced writeback -> barrier.

#define NB      131072
#define NUNITS  81
#define BPB     32             // batches per tile
#define THREADS 256
#define NTILES  (NB / BPB)     // 4096
#define PBLK    2048           // 8 per CU x 256 CUs; 2 tiles per block
#define REC     24             // floats per unit record (96 B)
#define CHUNKS  (BPB * 81 / 4) // 648 float4 per tile

typedef __attribute__((address_space(1))) const void GAS;
typedef __attribute__((address_space(3))) void LAS;
typedef float vfloat4 __attribute__((ext_vector_type(4)));

__global__ __launch_bounds__(256)
void logic_prep_kernel(const float* __restrict__ sa_logits,
                       const float* __restrict__ sb_logits,
                       const float* __restrict__ op_logits,
                       float* __restrict__ tab)
{
    const int tid = threadIdx.x;
    if (tid < 81) {
        const int u = tid;
        float v[9], m = -1e30f;
        #pragma unroll
        for (int i = 0; i < 9; ++i) { v[i] = sa_logits[u * 9 + i]; m = fmaxf(m, v[i]); }
        float s = 0.f;
        #pragma unroll
        for (int i = 0; i < 9; ++i) { v[i] = expf(v[i] - m); s += v[i]; }
        const float r = 1.f / s;
        #pragma unroll
        for (int i = 0; i < 9; ++i) tab[u * REC + i] = v[i] * r;
    } else if (tid < 162) {
        const int u = tid - 81;
        float v[9], m = -1e30f;
        #pragma unroll
        for (int i = 0; i < 9; ++i) { v[i] = sb_logits[u * 9 + i]; m = fmaxf(m, v[i]); }
        float s = 0.f;
        #pragma unroll
        for (int i = 0; i < 9; ++i) { v[i] = expf(v[i] - m); s += v[i]; }
        const float r = 1.f / s;
        #pragma unroll
        for (int i = 0; i < 9; ++i) tab[u * REC + 9 + i] = v[i] * r;
    } else if (tid < 243) {
        const int u = tid - 162;
        float v[16], m = -1e30f;
        #pragma unroll
        for (int i = 0; i < 16; ++i) { v[i] = op_logits[u * 16 + i]; m = fmaxf(m, v[i]); }
        float s = 0.f;
        #pragma unroll
        for (int i = 0; i < 16; ++i) { v[i] = expf(v[i] - m); s += v[i]; }
        const float r = 1.f / s;
        #pragma unroll
        for (int i = 0; i < 16; ++i) v[i] *= r;
        const float cab = v[1] - v[2] - v[4] - 2.f*v[6] - v[7] + v[8] + 2.f*v[9]
                        + v[11] + v[13] - v[14];
        const float ca  = v[2] + v[3] + v[6] + v[7] - v[8] - v[9] - v[12] - v[13];
        const float cb  = v[4] + v[5] + v[6] + v[7] - v[8] - v[9] - v[10] - v[11];
        const float c0  = v[8] + v[9] + v[10] + v[11] + v[12] + v[13] + v[14] + v[15];
        tab[u * REC + 18] = cab;
        tab[u * REC + 19] = ca;
        tab[u * REC + 20] = cb;
        tab[u * REC + 21] = c0;
    }
}

__global__ __launch_bounds__(THREADS, 8)
void logic_main_kernel(const float* __restrict__ x,
                       const float* __restrict__ tab,
                       float* __restrict__ out)
{
    __shared__ float s_tile[BPB * 81];     // 10368 B — the only LDS

    const int tid   = threadIdx.x;
    const int lane  = tid & 63;
    const int wavei = __builtin_amdgcn_readfirstlane(tid >> 6);

    #pragma unroll
    for (int tt = 0; tt < 2; ++tt) {
        const int t = blockIdx.x * 2 + tt;         // contiguous pair
        const size_t b0 = (size_t)t * BPB;

        if (tt) __syncthreads();                   // LDS protect vs prev writeback

        // ---- stage tile via global->LDS DMA ----
        {
            const float4* gsrc = (const float4*)(x + b0 * 81);
            #pragma unroll
            for (int k = 0; k < 3; ++k) {
                const int j = tid + k * THREADS;
                if (j < CHUNKS) {
                    // wave-uniform LDS base; hardware adds lane*16
                    float* lbase = s_tile + (size_t)(k * THREADS + wavei * 64) * 4;
                    __builtin_amdgcn_global_load_lds((GAS*)(gsrc + j), (LAS*)lbase,
                                                     16, 0, 0);
                }
            }
        }
        __syncthreads();

        // ---- compute: wave w<3, lanes<32; units 27w..27w+26 == patch-row w ----
        if (wavei < 3 && lane < BPB) {
            float* my = s_tile + lane * 81 + wavei * 27;   // read == write slice

            float in[27];                                   // img rows 3w..3w+2
            #pragma unroll
            for (int j = 0; j < 27; ++j) in[j] = my[j];

            const float4* __restrict__ wt4 =
                (const float4*)(tab + (size_t)wavei * 27 * REC);  // uniform base

            #pragma unroll
            for (int j = 0; j < 27; ++j) {                  // unit u = 27*wavei+j
                const int q = j / 9;                        // patch col within row
                const float4 q0 = wt4[j * 6 + 0];
                const float4 q1 = wt4[j * 6 + 1];
                const float4 q2 = wt4[j * 6 + 2];
                const float4 q3 = wt4[j * 6 + 3];
                const float4 q4 = wt4[j * 6 + 4];
                const float4 q5 = wt4[j * 6 + 5];
                const float wa[9] = { q0.x, q0.y, q0.z, q0.w, q1.x, q1.y, q1.z, q1.w, q2.x };
                const float wb[9] = { q2.y, q2.z, q2.w, q3.x, q3.y, q3.z, q3.w, q4.x, q4.y };
                float a = 0.f, b = 0.f;
                #pragma unroll
                for (int i = 0; i < 9; ++i) {
                    const float xi = in[q * 3 + (i / 3) * 9 + (i % 3)];
                    a = fmaf(xi, wa[i], a);
                    b = fmaf(xi, wb[i], b);
                }
                // q4.z=Cab q4.w=Ca q5.x=Cb q5.y=C0
                my[j] = fmaf(q4.z, a * b, fmaf(q4.w, a, fmaf(q5.x, b, q5.y)));
            }
        }

        __syncthreads();

        // ---- coalesced non-temporal writeback ----
        {
            const vfloat4* s4 = (const vfloat4*)s_tile;
            vfloat4* gdst = (vfloat4*)(out + b0 * 81);
            #pragma unroll
            for (int k = 0; k < 3; ++k) {
                const int j = tid + k * THREADS;
                if (j < CHUNKS) __builtin_nontemporal_store(s4[j], gdst + j);
            }
        }
    }
}

extern "C" void kernel_launch(void* const* d_in, const int* in_sizes, int n_in,
                              void* d_out, int out_size, void* d_ws, size_t ws_size,
                              hipStream_t stream)
{
    const float* x  = (const float*)d_in[0];
    const float* sa = (const float*)d_in[1];
    const float* sb = (const float*)d_in[2];
    const float* op = (const float*)d_in[3];
    float* tab  = (float*)d_ws;             // 81*24*4 = 7776 B
    float* outp = (float*)d_out;

    logic_prep_kernel<<<1, 256, 0, stream>>>(sa, sb, op, tab);
    logic_main_kernel<<<PBLK, THREADS, 0, stream>>>(x, tab, outp);
}

// Round 20
// 28.626 us; speedup vs baseline: 2.7947x; 1.0046x over previous
//
#include <hip/hip_runtime.h>
#include <math.h>

// LogicConv2d, prep + BALANCED persistent main at BPB=64.
//
// prep (1 block): softmax(sel_a), softmax(sel_b), collapse 16-way mix to
//   out = Cab*ab + Ca*a + Cb*b + C0. tab[81][24] floats in d_ws, readable
//   as 6 aligned float4 per unit: q0=sa[0:4] q1=sa[4:8] q2={sa8,sb0,sb1,sb2}
//   q3=sb[3:7] q4={sb7,sb8,Cab,Ca} q5={Cb,C0,-,-}.
//
// main: 1024 blocks x 256 threads; each block does EXACTLY 2 contiguous
//   tiles of 64 batches (t = 2*bid, 2*bid+1) — R16's 2048-on-1792 layout
//   left the final tile-round at 1/7 CU utilization; R19 showed balancing
//   via small tiles costs more than the tail, so this balances at BPB=64.
//   Per tile: global_load_lds DMA stage -> barrier -> compute (wave w<3:
//   units 27w..27w+26 == patch-row w; 27 inputs in regs; weights via
//   wave-uniform float4 loads, L2-hot; fully unrolled; in-place tile) ->
//   barrier -> NON-TEMPORAL coalesced writeback -> barrier (LDS protect).

#define NB      131072
#define NUNITS  81
#define BPB     64             // batches per tile
#define THREADS 256
#define NTILES  (NB / BPB)     // 2048
#define PBLK    1024           // blocks; exactly 2 tiles each
#define REC     24             // floats per unit record (96 B)
#define CHUNKS  (BPB * 81 / 4) // 1296 float4 per tile

typedef __attribute__((address_space(1))) const void GAS;
typedef __attribute__((address_space(3))) void LAS;
typedef float vfloat4 __attribute__((ext_vector_type(4)));

__global__ __launch_bounds__(256)
void logic_prep_kernel(const float* __restrict__ sa_logits,
                       const float* __restrict__ sb_logits,
                       const float* __restrict__ op_logits,
                       float* __restrict__ tab)
{
    const int tid = threadIdx.x;
    if (tid < 81) {
        const int u = tid;
        float v[9], m = -1e30f;
        #pragma unroll
        for (int i = 0; i < 9; ++i) { v[i] = sa_logits[u * 9 + i]; m = fmaxf(m, v[i]); }
        float s = 0.f;
        #pragma unroll
        for (int i = 0; i < 9; ++i) { v[i] = expf(v[i] - m); s += v[i]; }
        const float r = 1.f / s;
        #pragma unroll
        for (int i = 0; i < 9; ++i) tab[u * REC + i] = v[i] * r;
    } else if (tid < 162) {
        const int u = tid - 81;
        float v[9], m = -1e30f;
        #pragma unroll
        for (int i = 0; i < 9; ++i) { v[i] = sb_logits[u * 9 + i]; m = fmaxf(m, v[i]); }
        float s = 0.f;
        #pragma unroll
        for (int i = 0; i < 9; ++i) { v[i] = expf(v[i] - m); s += v[i]; }
        const float r = 1.f / s;
        #pragma unroll
        for (int i = 0; i < 9; ++i) tab[u * REC + 9 + i] = v[i] * r;
    } else if (tid < 243) {
        const int u = tid - 162;
        float v[16], m = -1e30f;
        #pragma unroll
        for (int i = 0; i < 16; ++i) { v[i] = op_logits[u * 16 + i]; m = fmaxf(m, v[i]); }
        float s = 0.f;
        #pragma unroll
        for (int i = 0; i < 16; ++i) { v[i] = expf(v[i] - m); s += v[i]; }
        const float r = 1.f / s;
        #pragma unroll
        for (int i = 0; i < 16; ++i) v[i] *= r;
        const float cab = v[1] - v[2] - v[4] - 2.f*v[6] - v[7] + v[8] + 2.f*v[9]
                        + v[11] + v[13] - v[14];
        const float ca  = v[2] + v[3] + v[6] + v[7] - v[8] - v[9] - v[12] - v[13];
        const float cb  = v[4] + v[5] + v[6] + v[7] - v[8] - v[9] - v[10] - v[11];
        const float c0  = v[8] + v[9] + v[10] + v[11] + v[12] + v[13] + v[14] + v[15];
        tab[u * REC + 18] = cab;
        tab[u * REC + 19] = ca;
        tab[u * REC + 20] = cb;
        tab[u * REC + 21] = c0;
    }
}

__global__ __launch_bounds__(THREADS, 7)
void logic_main_kernel(const float* __restrict__ x,
                       const float* __restrict__ tab,
                       float* __restrict__ out)
{
    __shared__ float s_tile[BPB * 81];     // 20736 B — the only LDS

    const int tid   = threadIdx.x;
    const int lane  = tid & 63;
    const int wavei = __builtin_amdgcn_readfirstlane(tid >> 6);

    #pragma unroll
    for (int tt = 0; tt < 2; ++tt) {
        const int t = blockIdx.x * 2 + tt;          // contiguous pair
        const size_t b0 = (size_t)t * BPB;

        if (tt) __syncthreads();                    // LDS protect vs prev writeback

        // ---- stage input tile via global->LDS DMA ----
        {
            const float4* gsrc = (const float4*)(x + b0 * 81);
            #pragma unroll
            for (int k = 0; k < 6; ++k) {
                const int j = tid + k * THREADS;
                if (j < CHUNKS) {
                    // wave-uniform LDS base; hardware adds lane*16
                    float* lbase = s_tile + (size_t)(k * THREADS + wavei * 64) * 4;
                    __builtin_amdgcn_global_load_lds((GAS*)(gsrc + j), (LAS*)lbase,
                                                     16, 0, 0);
                }
            }
        }
        __syncthreads();

        // ---- compute: wave w<3 owns units 27w..27w+26 (== patch-row w) ----
        if (wavei < 3) {
            float* my = s_tile + lane * 81 + wavei * 27;    // read == write slice

            float in[27];                                    // img rows 3w..3w+2
            #pragma unroll
            for (int j = 0; j < 27; ++j) in[j] = my[j];

            const float4* __restrict__ wt4 =
                (const float4*)(tab + (size_t)wavei * 27 * REC);  // uniform base

            #pragma unroll
            for (int j = 0; j < 27; ++j) {                   // unit u = 27*wavei+j
                const int q = j / 9;                         // patch col within row
                const float4 q0 = wt4[j * 6 + 0];
                const float4 q1 = wt4[j * 6 + 1];
                const float4 q2 = wt4[j * 6 + 2];
                const float4 q3 = wt4[j * 6 + 3];
                const float4 q4 = wt4[j * 6 + 4];
                const float4 q5 = wt4[j * 6 + 5];
                const float wa[9] = { q0.x, q0.y, q0.z, q0.w, q1.x, q1.y, q1.z, q1.w, q2.x };
                const float wb[9] = { q2.y, q2.z, q2.w, q3.x, q3.y, q3.z, q3.w, q4.x, q4.y };
                float a = 0.f, b = 0.f;
                #pragma unroll
                for (int i = 0; i < 9; ++i) {
                    const float xi = in[q * 3 + (i / 3) * 9 + (i % 3)];
                    a = fmaf(xi, wa[i], a);
                    b = fmaf(xi, wb[i], b);
                }
                // q4.z=Cab q4.w=Ca q5.x=Cb q5.y=C0
                my[j] = fmaf(q4.z, a * b, fmaf(q4.w, a, fmaf(q5.x, b, q5.y)));
            }
        }

        __syncthreads();

        // ---- coalesced non-temporal writeback ----
        {
            const vfloat4* s4 = (const vfloat4*)s_tile;
            vfloat4* gdst = (vfloat4*)(out + b0 * 81);
            #pragma unroll
            for (int k = 0; k < 6; ++k) {
                const int j = tid + k * THREADS;
                if (j < CHUNKS) __builtin_nontemporal_store(s4[j], gdst + j);
            }
        }
    }
}

extern "C" void kernel_launch(void* const* d_in, const int* in_sizes, int n_in,
                              void* d_out, int out_size, void* d_ws, size_t ws_size,
                              hipStream_t stream)
{
    const float* x  = (const float*)d_in[0];
    const float* sa = (const float*)d_in[1];
    const float* sb = (const float*)d_in[2];
    const float* op = (const float*)d_in[3];
    float* tab  = (float*)d_ws;             // 81*24*4 = 7776 B
    float* outp = (float*)d_out;

    logic_prep_kernel<<<1, 256, 0, stream>>>(sa, sb, op, tab);
    logic_main_kernel<<<PBLK, THREADS, 0, stream>>>(x, tab, outp);
}

// Round 21
// 26.742 us; speedup vs baseline: 2.9916x; 1.0705x over previous
//
#include <hip/hip_runtime.h>
#include <math.h>

// LogicConv2d — FINAL (R16 revert, measured best: 26.01 us).
//
// prep (1 block): softmax(sel_a), softmax(sel_b), collapse 16-way mix to
//   out = Cab*ab + Ca*a + Cb*b + C0. tab[81][24] floats in d_ws, readable as
//   6 aligned float4 per unit: q0=sa[0:4] q1=sa[4:8] q2={sa8,sb0,sb1,sb2}
//   q3=sb[3:7] q4={sb7,sb8,Cab,Ca} q5={Cb,C0,-,-}.
//
// main: 1792 persistent blocks (7/CU = LDS residency limit) x 256 threads;
//   each loops tiles t = bid, bid+1792 (64 batches/tile): global_load_lds
//   DMA staging -> barrier -> compute (wave w<3 owns units 27w..27w+26 ==
//   patch-row w; 27 inputs in regs; weights via wave-uniform float4 loads;
//   fully unrolled; in-place tile) -> barrier -> coalesced writeback with
//   NON-TEMPORAL stores -> barrier.
//
// 20-round ledger: wins = persistence (dispatch ramp/drain) + nt writeback
// (write-stream L3 pollution); falsified = weight path, LDS volume,
// occupancy, pipelining, tile size both ways, balance both ways, prep
// fusion x3, direct reads. All pipes <25% busy at this optimum — the
// residual is phase-latency + graph-replay overhead, not utilization.

#define NB      131072
#define NUNITS  81
#define BPB     64             // batches per tile
#define THREADS 256
#define NTILES  (NB / BPB)     // 2048
#define PBLK    1792           // persistent blocks = 7 per CU x 256 CUs
#define REC     24             // floats per unit record (96 B)
#define CHUNKS  (BPB * 81 / 4) // 1296 float4 per tile

typedef __attribute__((address_space(1))) const void GAS;
typedef __attribute__((address_space(3))) void LAS;
typedef float vfloat4 __attribute__((ext_vector_type(4)));

__global__ __launch_bounds__(256)
void logic_prep_kernel(const float* __restrict__ sa_logits,
                       const float* __restrict__ sb_logits,
                       const float* __restrict__ op_logits,
                       float* __restrict__ tab)
{
    const int tid = threadIdx.x;
    if (tid < 81) {
        const int u = tid;
        float v[9], m = -1e30f;
        #pragma unroll
        for (int i = 0; i < 9; ++i) { v[i] = sa_logits[u * 9 + i]; m = fmaxf(m, v[i]); }
        float s = 0.f;
        #pragma unroll
        for (int i = 0; i < 9; ++i) { v[i] = expf(v[i] - m); s += v[i]; }
        const float r = 1.f / s;
        #pragma unroll
        for (int i = 0; i < 9; ++i) tab[u * REC + i] = v[i] * r;
    } else if (tid < 162) {
        const int u = tid - 81;
        float v[9], m = -1e30f;
        #pragma unroll
        for (int i = 0; i < 9; ++i) { v[i] = sb_logits[u * 9 + i]; m = fmaxf(m, v[i]); }
        float s = 0.f;
        #pragma unroll
        for (int i = 0; i < 9; ++i) { v[i] = expf(v[i] - m); s += v[i]; }
        const float r = 1.f / s;
        #pragma unroll
        for (int i = 0; i < 9; ++i) tab[u * REC + 9 + i] = v[i] * r;
    } else if (tid < 243) {
        const int u = tid - 162;
        float v[16], m = -1e30f;
        #pragma unroll
        for (int i = 0; i < 16; ++i) { v[i] = op_logits[u * 16 + i]; m = fmaxf(m, v[i]); }
        float s = 0.f;
        #pragma unroll
        for (int i = 0; i < 16; ++i) { v[i] = expf(v[i] - m); s += v[i]; }
        const float r = 1.f / s;
        #pragma unroll
        for (int i = 0; i < 16; ++i) v[i] *= r;
        const float cab = v[1] - v[2] - v[4] - 2.f*v[6] - v[7] + v[8] + 2.f*v[9]
                        + v[11] + v[13] - v[14];
        const float ca  = v[2] + v[3] + v[6] + v[7] - v[8] - v[9] - v[12] - v[13];
        const float cb  = v[4] + v[5] + v[6] + v[7] - v[8] - v[9] - v[10] - v[11];
        const float c0  = v[8] + v[9] + v[10] + v[11] + v[12] + v[13] + v[14] + v[15];
        tab[u * REC + 18] = cab;
        tab[u * REC + 19] = ca;
        tab[u * REC + 20] = cb;
        tab[u * REC + 21] = c0;
    }
}

__global__ __launch_bounds__(THREADS, 7)
void logic_main_kernel(const float* __restrict__ x,
                       const float* __restrict__ tab,
                       float* __restrict__ out)
{
    __shared__ float s_tile[BPB * 81];     // 20736 B — the only LDS

    const int tid   = threadIdx.x;
    const int lane  = tid & 63;
    const int wavei = __builtin_amdgcn_readfirstlane(tid >> 6);

    for (int t = blockIdx.x; t < NTILES; t += PBLK) {
        const size_t b0 = (size_t)t * BPB;

        // ---- stage input tile via global->LDS DMA ----
        {
            const float4* gsrc = (const float4*)(x + b0 * 81);
            #pragma unroll
            for (int k = 0; k < 6; ++k) {
                const int j = tid + k * THREADS;
                if (j < CHUNKS) {
                    // wave-uniform LDS base; hardware adds lane*16
                    float* lbase = s_tile + (size_t)(k * THREADS + wavei * 64) * 4;
                    __builtin_amdgcn_global_load_lds((GAS*)(gsrc + j), (LAS*)lbase,
                                                     16, 0, 0);
                }
            }
        }
        __syncthreads();

        // ---- compute: wave w<3 owns units 27w..27w+26 (== patch-row w) ----
        if (wavei < 3) {
            float* my = s_tile + lane * 81 + wavei * 27;    // read == write slice

            float in[27];                                    // img rows 3w..3w+2
            #pragma unroll
            for (int j = 0; j < 27; ++j) in[j] = my[j];

            const float4* __restrict__ wt4 =
                (const float4*)(tab + (size_t)wavei * 27 * REC);  // uniform base

            #pragma unroll
            for (int j = 0; j < 27; ++j) {                   // unit u = 27*wavei+j
                const int q = j / 9;                         // patch col within row
                const float4 q0 = wt4[j * 6 + 0];
                const float4 q1 = wt4[j * 6 + 1];
                const float4 q2 = wt4[j * 6 + 2];
                const float4 q3 = wt4[j * 6 + 3];
                const float4 q4 = wt4[j * 6 + 4];
                const float4 q5 = wt4[j * 6 + 5];
                const float wa[9] = { q0.x, q0.y, q0.z, q0.w, q1.x, q1.y, q1.z, q1.w, q2.x };
                const float wb[9] = { q2.y, q2.z, q2.w, q3.x, q3.y, q3.z, q3.w, q4.x, q4.y };
                float a = 0.f, b = 0.f;
                #pragma unroll
                for (int i = 0; i < 9; ++i) {
                    const float xi = in[q * 3 + (i / 3) * 9 + (i % 3)];
                    a = fmaf(xi, wa[i], a);
                    b = fmaf(xi, wb[i], b);
                }
                // q4.z=Cab q4.w=Ca q5.x=Cb q5.y=C0
                my[j] = fmaf(q4.z, a * b, fmaf(q4.w, a, fmaf(q5.x, b, q5.y)));
            }
        }

        __syncthreads();

        // ---- coalesced writeback, all 4 waves, NON-TEMPORAL stores ----
        {
            const vfloat4* s4 = (const vfloat4*)s_tile;
            vfloat4* gdst = (vfloat4*)(out + b0 * 81);
            #pragma unroll
            for (int k = 0; k < 6; ++k) {
                const int j = tid + k * THREADS;
                if (j < CHUNKS) __builtin_nontemporal_store(s4[j], gdst + j);
            }
        }

        // protect the LDS tile from the next iteration's DMA
        __syncthreads();
    }
}

extern "C" void kernel_launch(void* const* d_in, const int* in_sizes, int n_in,
                              void* d_out, int out_size, void* d_ws, size_t ws_size,
                              hipStream_t stream)
{
    const float* x  = (const float*)d_in[0];
    const float* sa = (const float*)d_in[1];
    const float* sb = (const float*)d_in[2];
    const float* op = (const float*)d_in[3];
    float* tab  = (float*)d_ws;             // 81*24*4 = 7776 B
    float* outp = (float*)d_out;

    logic_prep_kernel<<<1, 256, 0, stream>>>(sa, sb, op, tab);
    logic_main_kernel<<<PBLK, THREADS, 0, stream>>>(x, tab, outp);
}